// Round 11
// baseline (286.033 us; speedup 1.0000x reference)
//
#include <hip/hip_runtime.h>
#include <math.h>

#define N 512
#define NN (N * N)
#define C 16
#define K 262144
#define LOG2N 9
#define CAP 640          // per-row bucket capacity: mean 512 + 5.7 sigma (Poisson), overflow ~4e-6
#define SROW (N + 2)     // padded LDS row stride (float4 units) to stagger banks across groups

// ============ fused prep + place: bucket points by row, no scan ============
// One kernel replaces prep_hist + 3 scan kernels + place. Each point claims a
// slot in its row's fixed-capacity bucket and writes a full-channel
// pre-weighted record pxv[p] = {w*x[c][k]} (128 B = 2 full lines) plus the
// pre-bit-reversed column pcw[p].
__global__ __launch_bounds__(256) void prep_place_kernel(const float2* __restrict__ traj,
                                                         const float* __restrict__ dcf,
                                                         const float* __restrict__ xr,
                                                         const float* __restrict__ xi,
                                                         int* __restrict__ rowcnt,
                                                         int* __restrict__ pcw,
                                                         float2* __restrict__ pxv) {
    int k = blockIdx.x * 256 + threadIdx.x;
    float2 t = traj[k];
    // jnp.round is half-to-even; __float2int_rn matches.
    int iy = __float2int_rn((t.x + 0.5f) * (float)N) & (N - 1);
    int ix = __float2int_rn((t.y + 0.5f) * (float)N) & (N - 1);
    float w = dcf[k] * (((iy + ix) & 1) ? -1.0f : 1.0f);   // ifftshift folded into sign
    int slot = atomicAdd(&rowcnt[iy], 1);
    if (slot >= CAP) return;                                // statistically unreachable guard
    size_t p = (size_t)iy * CAP + slot;
    pcw[p] = (int)(__brev((unsigned)ix) >> (32 - LOG2N));   // bit-reversed col
    float2* rec = pxv + p * C;
#pragma unroll
    for (int c = 0; c < C; ++c) {
        rec[c] = make_float2(xr[(size_t)c * K + k] * w, xi[(size_t)c * K + k] * w);
    }
}

// ============ shared fused radix-2^2 FFT core: 8 complex channels x 512, 512 thr ============
// s4[grp][pos]: float4 = {reA,imA,reB,imB} of a channel pair. Input bit-reversed,
// output natural order, +i exponent (inverse DFT, unnormalized). 5 barriers.
__device__ __forceinline__ void fft512x8(float4 (*s4)[SROW] , int t) {
    int g = t >> 7;                      // 0..3
    int u = t & 127;                     // butterfly within group
    for (int s = 1; s <= 7; s += 2) {
        int h = 1 << (s - 1);
        int j = u & (h - 1);
        int grp = u >> (s - 1);
        int p0 = grp * 4 * h + j;
        float th = 6.283185307179586f * (float)j / (float)(2 * h);
        float sW, cW, sV, cV;
        __sincosf(th, &sW, &cW);          // stage-s twiddle
        __sincosf(th * 0.5f, &sV, &cV);   // stage-(s+1) twiddle
        float4 A = s4[g][p0];
        float4 B = s4[g][p0 + h];
        float4 Cc = s4[g][p0 + 2 * h];
        float4 D = s4[g][p0 + 3 * h];
        float bx = cW * B.x - sW * B.y, by = cW * B.y + sW * B.x;
        float bz = cW * B.z - sW * B.w, bw = cW * B.w + sW * B.z;
        float4 A1 = make_float4(A.x + bx, A.y + by, A.z + bz, A.w + bw);
        float4 B1 = make_float4(A.x - bx, A.y - by, A.z - bz, A.w - bw);
        float dx = cW * D.x - sW * D.y, dy = cW * D.y + sW * D.x;
        float dz = cW * D.z - sW * D.w, dw = cW * D.w + sW * D.z;
        float4 C1 = make_float4(Cc.x + dx, Cc.y + dy, Cc.z + dz, Cc.w + dw);
        float4 D1 = make_float4(Cc.x - dx, Cc.y - dy, Cc.z - dz, Cc.w - dw);
        float cx = cV * C1.x - sV * C1.y, cy = cV * C1.y + sV * C1.x;
        float cz = cV * C1.z - sV * C1.w, cw = cV * C1.w + sV * C1.z;
        s4[g][p0]         = make_float4(A1.x + cx, A1.y + cy, A1.z + cz, A1.w + cw);
        s4[g][p0 + 2 * h] = make_float4(A1.x - cx, A1.y - cy, A1.z - cz, A1.w - cw);
        float ex = cV * D1.x - sV * D1.y, ey = cV * D1.y + sV * D1.x;
        float ez = cV * D1.z - sV * D1.w, ew = cV * D1.w + sV * D1.z;
        // i*(ex + i ey) = (-ey, ex)
        s4[g][p0 + h]     = make_float4(B1.x - ey, B1.y + ex, B1.z - ew, B1.w + ez);
        s4[g][p0 + 3 * h] = make_float4(B1.x + ey, B1.y - ex, B1.z + ew, B1.w - ez);
        __syncthreads();
    }
    // final radix-2 stage (s=9, half=256): 1024 units, 2 per thread
    {
        int bb = t & 255;
        int gg = t >> 8;                 // 0..1
        float th = 6.283185307179586f * (float)bb / 512.0f;
        float sn, cs;
        __sincosf(th, &sn, &cs);
#pragma unroll
        for (int gi = 0; gi < 2; ++gi) {
            int g9 = gg + 2 * gi;
            float4 uu = s4[g9][bb];
            float4 vv = s4[g9][bb + 256];
            float tra = cs * vv.x - sn * vv.y;
            float tia = cs * vv.y + sn * vv.x;
            float trb = cs * vv.z - sn * vv.w;
            float tib = cs * vv.w + sn * vv.z;
            s4[g9][bb + 256] = make_float4(uu.x - tra, uu.y - tia, uu.z - trb, uu.w - tib);
            s4[g9][bb]       = make_float4(uu.x + tra, uu.y + tia, uu.z + trb, uu.w + tib);
        }
        __syncthreads();
    }
}

// ============ fused grid-build + row FFT: 8 channels per block ============
// block = (row r, half g2), 512 threads. Scatter: 4-lane teams split each 64 B
// half-record into 16 B cached (NOT nontemporal) loads -> dense full-line,
// L1-coalesced requests. LDS scatter at pre-bit-reversed column, then FFT.
__global__ __launch_bounds__(512) void build_rowfft_kernel(const int* __restrict__ rowcnt,
                                                           const int* __restrict__ pcw,
                                                           const float2* __restrict__ pxv,
                                                           float2* __restrict__ grid) {
    __shared__ float4 s4[4][SROW];       // ~33 KB
    int b = blockIdx.x;
    int g2 = b & 1;                      // which 8-channel half
    int r = b >> 1;
    int t = threadIdx.x;

    for (int i = t; i < N; i += 512) {
        s4[0][i] = make_float4(0.f, 0.f, 0.f, 0.f);
        s4[1][i] = make_float4(0.f, 0.f, 0.f, 0.f);
        s4[2][i] = make_float4(0.f, 0.f, 0.f, 0.f);
        s4[3][i] = make_float4(0.f, 0.f, 0.f, 0.f);
    }
    int cnt = rowcnt[r];
    if (cnt > CAP) cnt = CAP;
    int base = r * CAP;
    __syncthreads();

    // 4-lane team per point: lane sub handles f4 #sub of this half-record
    const float4* pxv4 = (const float4*)pxv;     // record = 8 x float4
    int sub = t & 3;
    for (int q = t >> 2; q < cnt; q += 128) {
        int p = base + q;
        int bc = pcw[p];                          // 4 lanes same addr -> broadcast
        float4 v = pxv4[(size_t)p * 8 + g2 * 4 + sub];
        atomicAdd(&s4[sub][bc].x, v.x);
        atomicAdd(&s4[sub][bc].y, v.y);
        atomicAdd(&s4[sub][bc].z, v.z);
        atomicAdd(&s4[sub][bc].w, v.w);
    }
    __syncthreads();

    fft512x8(s4, t);

#pragma unroll
    for (int g4 = 0; g4 < 4; ++g4) {
        int ca = g2 * 8 + 2 * g4;
        float2* ga = grid + (size_t)ca * NN + (size_t)r * N;
        float2* gb = grid + (size_t)(ca + 1) * NN + (size_t)r * N;
        for (int i = t; i < N; i += 512) {
            float4 v = s4[g4][i];
            ga[i] = make_float2(v.x, v.y);
            gb[i] = make_float2(v.z, v.w);
        }
    }
}

// ============ column FFT: 8 columns (4 col-pairs) per block, 512 threads ============
__global__ __launch_bounds__(512) void colfft_kernel(float2* __restrict__ grid) {
    __shared__ float4 s4[4][SROW];
    int blk = blockIdx.x;                        // c * 64 + strip
    int c = blk >> 6;
    int cg = blk & 63;
    float4* base4 = (float4*)(grid + (size_t)c * NN + cg * 8);   // 16 B aligned
    int t = threadIdx.x;

    // load: float4 = cols {2pr, 2pr+1} of one row
    for (int e = t; e < 4 * N; e += 512) {
        int row = e >> 2, pr = e & 3;
        s4[pr][row] = base4[(size_t)row * (N / 2) + pr];
    }
    __syncthreads();

    // bit-reversal permutation
    {
        int g = t >> 7, u = t & 127;
        for (int i = u; i < N; i += 128) {
            int j = (int)(__brev((unsigned)i) >> (32 - LOG2N));
            if (j > i) {
                float4 a = s4[g][i];
                s4[g][i] = s4[g][j];
                s4[g][j] = a;
            }
        }
    }
    __syncthreads();

    fft512x8(s4, t);

    for (int e = t; e < 4 * N; e += 512) {
        int row = e >> 2, pr = e & 3;
        base4[(size_t)row * (N / 2) + pr] = s4[pr][row];
    }
}

// ============ combine: out = (-1)^(ny+nx) * sum_c conj(csm)*img, 2 px/thread ============
__global__ __launch_bounds__(256) void combine_kernel(const float* __restrict__ csr,
                                                      const float* __restrict__ csi,
                                                      const float2* __restrict__ grid,
                                                      float* __restrict__ out) {
    int i2 = blockIdx.x * 256 + threadIdx.x;     // float4/pixel-pair index, 0..NN/2
    int pix = i2 * 2;
    int ny = pix >> LOG2N, nx = pix & (N - 1);
    const float4* g4 = (const float4*)grid;
    const float2* cr2 = (const float2*)csr;
    const float2* ci2 = (const float2*)csi;
    float ar0 = 0.f, ai0 = 0.f, ar1 = 0.f, ai1 = 0.f;
#pragma unroll
    for (int c = 0; c < C; ++c) {
        float4 uv = g4[(size_t)c * (NN / 2) + i2];   // {re0,im0,re1,im1}
        float2 a = cr2[(size_t)c * (NN / 2) + i2];
        float2 b = ci2[(size_t)c * (NN / 2) + i2];
        ar0 += a.x * uv.x + b.x * uv.y;
        ai0 += a.x * uv.y - b.x * uv.x;
        ar1 += a.y * uv.z + b.y * uv.w;
        ai1 += a.y * uv.w - b.y * uv.z;
    }
    float s = ((ny + nx) & 1) ? -1.f : 1.f;      // fftshift; pix+1 flips sign
    float2* o2 = (float2*)out;
    o2[i2] = make_float2(s * ar0, -s * ar1);
    o2[NN / 2 + i2] = make_float2(s * ai0, -s * ai1);
}

extern "C" void kernel_launch(void* const* d_in, const int* in_sizes, int n_in,
                              void* d_out, int out_size, void* d_ws, size_t ws_size,
                              hipStream_t stream) {
    const float* x_real   = (const float*)d_in[0];
    const float* x_imag   = (const float*)d_in[1];
    const float* csm_real = (const float*)d_in[2];
    const float* csm_imag = (const float*)d_in[3];
    const float2* traj    = (const float2*)d_in[4];
    const float* dcf      = (const float*)d_in[5];
    float* out = (float*)d_out;

    char* ws = (char*)d_ws;
    size_t o = 0;
    float* grid   = (float*)(ws + o);  o += (size_t)C * NN * 2 * sizeof(float);       // 32 MB
    float2* pxv   = (float2*)(ws + o); o += (size_t)N * CAP * C * sizeof(float2);     // 40 MB
    int*   pcw    = (int*)(ws + o);    o += (size_t)N * CAP * sizeof(int);            // 1.25 MB
    int*   rowcnt = (int*)(ws + o);    o += (size_t)N * sizeof(int);                  // 2 KB

    (void)hipMemsetAsync(rowcnt, 0, (size_t)N * sizeof(int), stream);

    prep_place_kernel<<<K / 256, 256, 0, stream>>>(traj, dcf, x_real, x_imag,
                                                   rowcnt, pcw, pxv);
    build_rowfft_kernel<<<N * 2, 512, 0, stream>>>(rowcnt, pcw, pxv, (float2*)grid);
    colfft_kernel<<<C * (N / 8), 512, 0, stream>>>((float2*)grid);
    combine_kernel<<<(NN / 2) / 256, 256, 0, stream>>>(csm_real, csm_imag,
                                                       (float2*)grid, out);
}

// Round 12
// 278.117 us; speedup vs baseline: 1.0285x; 1.0285x over previous
//
#include <hip/hip_runtime.h>
#include <math.h>

#define N 512
#define NN (N * N)
#define C 16
#define K 262144
#define LOG2N 9
#define CAP 640          // per-row bucket capacity: mean 512 + 5.7 sigma (Poisson), overflow ~4e-6
#define SROW (N + 2)     // padded LDS row stride (float4 units) for FFT kernels

// ============ fused prep + place, LDS-staged coalesced record write ============
// Phase 1: thread = point. Coalesced x reads; stage record (8 x float4) in LDS;
// claim row-bucket slot. Phase 2: 8-lane teams write each 128 B record with 8
// contiguous 16 B lane-stores -> exactly 2 full-line transactions per point
// (vs 17 scattered small stores = the R11 105 us transaction bottleneck).
__global__ __launch_bounds__(256) void prep_place_kernel(const float2* __restrict__ traj,
                                                         const float* __restrict__ dcf,
                                                         const float* __restrict__ xr,
                                                         const float* __restrict__ xi,
                                                         int* __restrict__ rowcnt,
                                                         int* __restrict__ pcw,
                                                         float4* __restrict__ pxv4) {
    __shared__ float4 lrec[256][8];      // 32 KB staged records
    __shared__ int spt[256];             // destination slot per point
    int tid = threadIdx.x;
    int k = blockIdx.x * 256 + tid;

    float2 t = traj[k];
    // jnp.round is half-to-even; __float2int_rn matches.
    int iy = __float2int_rn((t.x + 0.5f) * (float)N) & (N - 1);
    int ix = __float2int_rn((t.y + 0.5f) * (float)N) & (N - 1);
    float w = dcf[k] * (((iy + ix) & 1) ? -1.0f : 1.0f);   // ifftshift folded into sign

    int slot = atomicAdd(&rowcnt[iy], 1);
    if (slot < CAP) {
        int p = iy * CAP + slot;
        spt[tid] = p;
        pcw[p] = (int)(__brev((unsigned)ix) >> (32 - LOG2N));   // bit-reversed col
    } else {
        spt[tid] = -1;                   // statistically unreachable
    }
#pragma unroll
    for (int j = 0; j < 8; ++j) {        // channel pair (2j, 2j+1)
        float a = xr[(size_t)(2 * j) * K + k] * w;
        float b = xi[(size_t)(2 * j) * K + k] * w;
        float c = xr[(size_t)(2 * j + 1) * K + k] * w;
        float d = xi[(size_t)(2 * j + 1) * K + k] * w;
        lrec[tid][j] = make_float4(a, b, c, d);
    }
    __syncthreads();

    // 8-lane teams stream records out: 128 B contiguous per point
    int sub = tid & 7;
    for (int pt = tid >> 3; pt < 256; pt += 32) {
        int p = spt[pt];
        if (p >= 0) pxv4[(size_t)p * 8 + sub] = lrec[pt][sub];
    }
}

// ============ shared fused radix-2^2 FFT core: 8 complex channels x 512, 512 thr ============
// s4[grp][pos]: float4 = {reA,imA,reB,imB} of a channel pair. Input bit-reversed,
// output natural order, +i exponent (inverse DFT, unnormalized). 5 barriers.
__device__ __forceinline__ void fft512x8(float4 (*s4)[SROW], int t) {
    int g = t >> 7;                      // 0..3
    int u = t & 127;                     // butterfly within group
    for (int s = 1; s <= 7; s += 2) {
        int h = 1 << (s - 1);
        int j = u & (h - 1);
        int grp = u >> (s - 1);
        int p0 = grp * 4 * h + j;
        float th = 6.283185307179586f * (float)j / (float)(2 * h);
        float sW, cW, sV, cV;
        __sincosf(th, &sW, &cW);          // stage-s twiddle
        __sincosf(th * 0.5f, &sV, &cV);   // stage-(s+1) twiddle
        float4 A = s4[g][p0];
        float4 B = s4[g][p0 + h];
        float4 Cc = s4[g][p0 + 2 * h];
        float4 D = s4[g][p0 + 3 * h];
        float bx = cW * B.x - sW * B.y, by = cW * B.y + sW * B.x;
        float bz = cW * B.z - sW * B.w, bw = cW * B.w + sW * B.z;
        float4 A1 = make_float4(A.x + bx, A.y + by, A.z + bz, A.w + bw);
        float4 B1 = make_float4(A.x - bx, A.y - by, A.z - bz, A.w - bw);
        float dx = cW * D.x - sW * D.y, dy = cW * D.y + sW * D.x;
        float dz = cW * D.z - sW * D.w, dw = cW * D.w + sW * D.z;
        float4 C1 = make_float4(Cc.x + dx, Cc.y + dy, Cc.z + dz, Cc.w + dw);
        float4 D1 = make_float4(Cc.x - dx, Cc.y - dy, Cc.z - dz, Cc.w - dw);
        float cx = cV * C1.x - sV * C1.y, cy = cV * C1.y + sV * C1.x;
        float cz = cV * C1.z - sV * C1.w, cw = cV * C1.w + sV * C1.z;
        s4[g][p0]         = make_float4(A1.x + cx, A1.y + cy, A1.z + cz, A1.w + cw);
        s4[g][p0 + 2 * h] = make_float4(A1.x - cx, A1.y - cy, A1.z - cz, A1.w - cw);
        float ex = cV * D1.x - sV * D1.y, ey = cV * D1.y + sV * D1.x;
        float ez = cV * D1.z - sV * D1.w, ew = cV * D1.w + sV * D1.z;
        // i*(ex + i ey) = (-ey, ex)
        s4[g][p0 + h]     = make_float4(B1.x - ey, B1.y + ex, B1.z - ew, B1.w + ez);
        s4[g][p0 + 3 * h] = make_float4(B1.x + ey, B1.y - ex, B1.z + ew, B1.w - ez);
        __syncthreads();
    }
    // final radix-2 stage (s=9, half=256): 1024 units, 2 per thread
    {
        int bb = t & 255;
        int gg = t >> 8;                 // 0..1
        float th = 6.283185307179586f * (float)bb / 512.0f;
        float sn, cs;
        __sincosf(th, &sn, &cs);
#pragma unroll
        for (int gi = 0; gi < 2; ++gi) {
            int g9 = gg + 2 * gi;
            float4 uu = s4[g9][bb];
            float4 vv = s4[g9][bb + 256];
            float tra = cs * vv.x - sn * vv.y;
            float tia = cs * vv.y + sn * vv.x;
            float trb = cs * vv.z - sn * vv.w;
            float tib = cs * vv.w + sn * vv.z;
            s4[g9][bb + 256] = make_float4(uu.x - tra, uu.y - tia, uu.z - trb, uu.w - tib);
            s4[g9][bb]       = make_float4(uu.x + tra, uu.y + tia, uu.z + trb, uu.w + tib);
        }
        __syncthreads();
    }
}

// ============ fused grid-build + row FFT: 8 channels per block ============
// block = (row r, half g2), 512 threads. Scatter: 4-lane teams split each 64 B
// half-record into 16 B cached loads -> dense full-line requests. LDS scatter
// at pre-bit-reversed column, then FFT.
__global__ __launch_bounds__(512) void build_rowfft_kernel(const int* __restrict__ rowcnt,
                                                           const int* __restrict__ pcw,
                                                           const float4* __restrict__ pxv4,
                                                           float2* __restrict__ grid) {
    __shared__ float4 s4[4][SROW];       // ~33 KB
    int b = blockIdx.x;
    int g2 = b & 1;                      // which 8-channel half
    int r = b >> 1;
    int t = threadIdx.x;

    for (int i = t; i < N; i += 512) {
        s4[0][i] = make_float4(0.f, 0.f, 0.f, 0.f);
        s4[1][i] = make_float4(0.f, 0.f, 0.f, 0.f);
        s4[2][i] = make_float4(0.f, 0.f, 0.f, 0.f);
        s4[3][i] = make_float4(0.f, 0.f, 0.f, 0.f);
    }
    int cnt = rowcnt[r];
    if (cnt > CAP) cnt = CAP;
    int base = r * CAP;
    __syncthreads();

    // 4-lane team per point: lane sub handles f4 #sub of this half-record
    int sub = t & 3;
    for (int q = t >> 2; q < cnt; q += 128) {
        int p = base + q;
        int bc = pcw[p];                          // 4 lanes same addr -> broadcast
        float4 v = pxv4[(size_t)p * 8 + g2 * 4 + sub];
        atomicAdd(&s4[sub][bc].x, v.x);
        atomicAdd(&s4[sub][bc].y, v.y);
        atomicAdd(&s4[sub][bc].z, v.z);
        atomicAdd(&s4[sub][bc].w, v.w);
    }
    __syncthreads();

    fft512x8(s4, t);

#pragma unroll
    for (int g4 = 0; g4 < 4; ++g4) {
        int ca = g2 * 8 + 2 * g4;
        float2* ga = grid + (size_t)ca * NN + (size_t)r * N;
        float2* gb = grid + (size_t)(ca + 1) * NN + (size_t)r * N;
        for (int i = t; i < N; i += 512) {
            float4 v = s4[g4][i];
            ga[i] = make_float2(v.x, v.y);
            gb[i] = make_float2(v.z, v.w);
        }
    }
}

// ============ column FFT: 8 columns (4 col-pairs) per block, 512 threads ============
__global__ __launch_bounds__(512) void colfft_kernel(float2* __restrict__ grid) {
    __shared__ float4 s4[4][SROW];
    int blk = blockIdx.x;                        // c * 64 + strip
    int c = blk >> 6;
    int cg = blk & 63;
    float4* base4 = (float4*)(grid + (size_t)c * NN + cg * 8);   // 16 B aligned
    int t = threadIdx.x;

    // load: float4 = cols {2pr, 2pr+1} of one row
    for (int e = t; e < 4 * N; e += 512) {
        int row = e >> 2, pr = e & 3;
        s4[pr][row] = base4[(size_t)row * (N / 2) + pr];
    }
    __syncthreads();

    // bit-reversal permutation
    {
        int g = t >> 7, u = t & 127;
        for (int i = u; i < N; i += 128) {
            int j = (int)(__brev((unsigned)i) >> (32 - LOG2N));
            if (j > i) {
                float4 a = s4[g][i];
                s4[g][i] = s4[g][j];
                s4[g][j] = a;
            }
        }
    }
    __syncthreads();

    fft512x8(s4, t);

    for (int e = t; e < 4 * N; e += 512) {
        int row = e >> 2, pr = e & 3;
        base4[(size_t)row * (N / 2) + pr] = s4[pr][row];
    }
}

// ============ combine: out = (-1)^(ny+nx) * sum_c conj(csm)*img, 2 px/thread ============
__global__ __launch_bounds__(256) void combine_kernel(const float* __restrict__ csr,
                                                      const float* __restrict__ csi,
                                                      const float2* __restrict__ grid,
                                                      float* __restrict__ out) {
    int i2 = blockIdx.x * 256 + threadIdx.x;     // pixel-pair index, 0..NN/2
    int pix = i2 * 2;
    int ny = pix >> LOG2N, nx = pix & (N - 1);
    const float4* g4 = (const float4*)grid;
    const float2* cr2 = (const float2*)csr;
    const float2* ci2 = (const float2*)csi;
    float ar0 = 0.f, ai0 = 0.f, ar1 = 0.f, ai1 = 0.f;
#pragma unroll
    for (int c = 0; c < C; ++c) {
        float4 uv = g4[(size_t)c * (NN / 2) + i2];   // {re0,im0,re1,im1}
        float2 a = cr2[(size_t)c * (NN / 2) + i2];
        float2 b = ci2[(size_t)c * (NN / 2) + i2];
        ar0 += a.x * uv.x + b.x * uv.y;
        ai0 += a.x * uv.y - b.x * uv.x;
        ar1 += a.y * uv.z + b.y * uv.w;
        ai1 += a.y * uv.w - b.y * uv.z;
    }
    float s = ((ny + nx) & 1) ? -1.f : 1.f;      // fftshift; pix+1 flips sign
    float2* o2 = (float2*)out;
    o2[i2] = make_float2(s * ar0, -s * ar1);
    o2[NN / 2 + i2] = make_float2(s * ai0, -s * ai1);
}

extern "C" void kernel_launch(void* const* d_in, const int* in_sizes, int n_in,
                              void* d_out, int out_size, void* d_ws, size_t ws_size,
                              hipStream_t stream) {
    const float* x_real   = (const float*)d_in[0];
    const float* x_imag   = (const float*)d_in[1];
    const float* csm_real = (const float*)d_in[2];
    const float* csm_imag = (const float*)d_in[3];
    const float2* traj    = (const float2*)d_in[4];
    const float* dcf      = (const float*)d_in[5];
    float* out = (float*)d_out;

    char* ws = (char*)d_ws;
    size_t o = 0;
    float* grid   = (float*)(ws + o);  o += (size_t)C * NN * 2 * sizeof(float);       // 32 MB
    float4* pxv4  = (float4*)(ws + o); o += (size_t)N * CAP * 8 * sizeof(float4);     // 40 MB
    int*   pcw    = (int*)(ws + o);    o += (size_t)N * CAP * sizeof(int);            // 1.25 MB
    int*   rowcnt = (int*)(ws + o);    o += (size_t)N * sizeof(int);                  // 2 KB

    (void)hipMemsetAsync(rowcnt, 0, (size_t)N * sizeof(int), stream);

    prep_place_kernel<<<K / 256, 256, 0, stream>>>(traj, dcf, x_real, x_imag,
                                                   rowcnt, pcw, pxv4);
    build_rowfft_kernel<<<N * 2, 512, 0, stream>>>(rowcnt, pcw, pxv4, (float2*)grid);
    colfft_kernel<<<C * (N / 8), 512, 0, stream>>>((float2*)grid);
    combine_kernel<<<(NN / 2) / 256, 256, 0, stream>>>(csm_real, csm_imag,
                                                       (float2*)grid, out);
}